// Round 7
// baseline (794.947 us; speedup 1.0000x reference)
//
#include <hip/hip_runtime.h>
#include <hip/hip_bf16.h>
#include <stdint.h>

// ============================================================================
// MultiHeadedAttention  T=2048 B=4 K=512 H=8   (bf16 MFMA pipeline, chunked)
//
//   prep_x:   x f32 -> xb bf16 [8192 x 512]
//   prep_w:   Wq/Wk/Wv f32 -> Wt bf16 [3][4096][512] (transposed)
//   per chunk c (h0 = c*CHH):
//     gemm_proj8: Qc/Kc/Vc = (xb @ W + b)*scale   [8192 x CW]  (256^2 8-phase)
//     transpose:  Vc -> Vtc[zc][d][t]
//     gemm_s8:    E = exp(Q K^T), L += rowsum     (256^2 8-phase)
//     gemm_pv:    ctxc = (E @ Vt^T)/L             (128^2 2-phase)
//     out_gemm:   out (+)= ctxc @ Wo (+ bo on first chunk)
//
// 8-phase core (guide §5 template, T2+T3+T4+T5): 512 thr = 8 waves (2M x 4N),
// wave out 128x64, BK=64, LDS 128 KiB dynamic = 2 dbuf x (A 32K + B 32K).
// Counted vmcnt(6) at phases 4/8 only (vmcnt(0) on last iter: stages skipped).
// ws tiers: >=309MiB CHH=4,NZ=16 | >=165 CHH=2,NZ=8 | >=93 CHH=1,NZ=4
//           | else CHH=1,NZ=1 (floor 68.25 MiB).
// ============================================================================

typedef __bf16 bf16_t;
typedef __bf16 bf16x8 __attribute__((ext_vector_type(8)));
using short8 = __attribute__((ext_vector_type(8))) short;   // MFMA A/B frag
typedef float  f32x4  __attribute__((ext_vector_type(4)));
typedef uint32_t u32;

#define T_N 2048
#define K_N 512
#define F_N 4096
#define SCALE_QK 0.21022410381342863f   // 512^-0.25

#define AS3 __attribute__((address_space(3)))
#define AS1 __attribute__((address_space(1)))

__device__ __forceinline__ void gll16(const void* gsrc, void* ldst) {
  __builtin_amdgcn_global_load_lds((const AS1 u32*)gsrc, (AS3 u32*)ldst, 16, 0, 0);
}

#define SB   __builtin_amdgcn_s_barrier()
#define WLG  do { asm volatile("s_waitcnt lgkmcnt(0)" ::: "memory"); \
                  __builtin_amdgcn_sched_barrier(0); } while (0)
#define PRI1 __builtin_amdgcn_s_setprio(1)
#define PRI0 __builtin_amdgcn_s_setprio(0)
#define VM6  asm volatile("s_waitcnt vmcnt(6)" ::: "memory")
#define VM0  asm volatile("s_waitcnt vmcnt(0)" ::: "memory")

// ---------------------------------------------------------------------------
__global__ void prep_x(const float* __restrict__ x, bf16_t* __restrict__ xb) {
  int i = (blockIdx.x * 256 + threadIdx.x) * 8;
  float4 a = *(const float4*)(x + i);
  float4 b = *(const float4*)(x + i + 4);
  bf16x8 o;
  o[0] = (bf16_t)a.x; o[1] = (bf16_t)a.y; o[2] = (bf16_t)a.z; o[3] = (bf16_t)a.w;
  o[4] = (bf16_t)b.x; o[5] = (bf16_t)b.y; o[6] = (bf16_t)b.z; o[7] = (bf16_t)b.w;
  *(bf16x8*)(xb + i) = o;
}

// W [512][4096] f32 -> Wt [4096][512] bf16 (per z in {q,k,v})
__global__ void prep_w(const float* __restrict__ Wq, const float* __restrict__ Wk,
                       const float* __restrict__ Wv, bf16_t* __restrict__ Wt) {
  const float* W = blockIdx.z == 0 ? Wq : (blockIdx.z == 1 ? Wk : Wv);
  bf16_t* out = Wt + (size_t)blockIdx.z * F_N * K_N;
  __shared__ alignas(16) bf16_t tile[64][72];
  int k0 = blockIdx.x * 64, f0 = blockIdx.y * 64;
  int tid = threadIdx.x;
  int r = tid >> 3, cc = (tid & 7) * 8;
#pragma unroll
  for (int h = 0; h < 2; h++) {
    int rr = r + h * 32;  // k-local
    const float* src = W + (size_t)(k0 + rr) * F_N + f0 + cc;
    float4 a = *(const float4*)src;
    float4 b = *(const float4*)(src + 4);
    bf16_t* d = &tile[rr][cc];
    d[0] = (bf16_t)a.x; d[1] = (bf16_t)a.y; d[2] = (bf16_t)a.z; d[3] = (bf16_t)a.w;
    d[4] = (bf16_t)b.x; d[5] = (bf16_t)b.y; d[6] = (bf16_t)b.z; d[7] = (bf16_t)b.w;
  }
  __syncthreads();
#pragma unroll
  for (int h = 0; h < 2; h++) {
    int rr = r + h * 32;  // f-local
    bf16x8 o;
#pragma unroll
    for (int j = 0; j < 8; j++) o[j] = tile[cc + j][rr];
    *(bf16x8*)(out + (size_t)(f0 + rr) * K_N + k0 + cc) = o;
  }
}

__global__ void zero_l(float* l) { l[blockIdx.x * 256 + threadIdx.x] = 0.0f; }

// Vc [8192][CW] (row r = t*4+b) -> Vtc [zc][512][2048], zc: b=zc&3, hh=zc>>2
template <int CHH>
__global__ void transpose_v_t(const bf16_t* __restrict__ Vc, bf16_t* __restrict__ Vtc) {
  constexpr int CW = CHH * 512;
  int zc = blockIdx.z, b = zc & 3, hh = zc >> 2;
  int t0 = blockIdx.x * 64, d0 = blockIdx.y * 64;
  __shared__ alignas(16) bf16_t tile[64][72];
  int tid = threadIdx.x;
  int r = tid >> 3, cc = (tid & 7) * 8;
#pragma unroll
  for (int h = 0; h < 2; h++) {
    int rr = r + h * 32;  // t-local
    *(bf16x8*)&tile[rr][cc] = *(const bf16x8*)(
        Vc + (size_t)(t0 + rr) * 4 * CW + (size_t)b * CW + hh * 512 + d0 + cc);
  }
  __syncthreads();
  bf16_t* out = Vtc + (size_t)zc * K_N * T_N;
#pragma unroll
  for (int h = 0; h < 2; h++) {
    int rr = r + h * 32;  // d-local
    bf16x8 o;
#pragma unroll
    for (int j = 0; j < 8; j++) o[j] = tile[cc + j][rr];
    *(bf16x8*)(out + (size_t)(d0 + rr) * T_N + t0 + cc) = o;
  }
}

// ---------------------------------------------------------------------------
// 256^2 8-phase B^T GEMM core. C[256x256] = A[m][k] * B[n][k]^T, bf16, f32 acc.
// 8 waves: wr=wid>>2 (M), wc=wid&3 (N). Wave frags: rows mh*128+wr*64+j*16,
// cols nh*128+wc*32+j2*16. Phase p computes quadrant (mh,nh) of one K-tile;
// per-phase stage of one half-tile (2 x gll16); vmcnt(6) at P4/P8.
// LDS: buf b @ smem+b*65536, A @ +0, B @ +32768, half h @ +h*16384.
// XOR swizzle byte^=((row&7)<<4), pre-swizzled global source (rule #21).
// vmcnt ledger (desk-verified r4/r5): prologue 14->VM6 leaves t1{Ah0,Bh0,Bh1};
// steady P4/P8 at 14->VM6 completes exactly the 8 loads of the next-read
// tile; last-iter skipped stages -> VM0 branch. WAR (r5): a wave's ds_reads
// complete under its own lgkmcnt(0) before its phase-closing barrier; any
// STG overwrite issues only after 2+ more barriers. Barrier count uniform
// (STG early-out and VM6/VM0 branches are wave-uniform). Raw s_barrier has
// no implicit waitcnt drain (r6) — loads intentionally span barriers.
// ---------------------------------------------------------------------------
template <int NKT>
__device__ __forceinline__ void gemm_bt_8ph(
    const char* __restrict__ Ab, int sA, const char* __restrict__ Bb, int sB,
    int mbase, int nbase, char* smem, f32x4 (&acc)[8][4]) {
  static_assert(NKT >= 4 && (NKT & 1) == 0, "NKT even >= 4");
  const int lane = threadIdx.x & 63;
  const int wid  = threadIdx.x >> 6;
  const int wr   = wid >> 2, wc = wid & 3;
  const int rl   = lane & 15;
  const int kg   = (lane >> 4) * 16;
  const int sx   = (rl & 7) << 4;          // ds_read swizzle
  const int srow = lane >> 3;              // stage row-in-8
  const int scol = (lane & 7) * 16;
  const int sxs  = srow << 4;              // stage source pre-swizzle (= (row&7)<<4)

#pragma unroll
  for (int i = 0; i < 8; i++)
#pragma unroll
    for (int j = 0; j < 4; j++) acc[i][j] = f32x4{0.f, 0.f, 0.f, 0.f};

  // stage one 128-row half of A(mat=0)/B(mat=1) of K-tile kt into buf kt&1
  auto STG = [&](int mat, int half, int kt) {
    if (kt >= NKT) return;
    char* dst = smem + (kt & 1) * 65536 + mat * 32768 + half * 16384 + wid * 1024;
    const char* gb = mat ? Bb : Ab;
    int s = mat ? sB : sA;
    int rb = (mat ? nbase : mbase) + half * 128;
#pragma unroll
    for (int j = 0; j < 2; j++) {
      int r = j * 64 + wid * 8 + srow;
      gll16(gb + (size_t)(rb + r) * s + kt * 128 + (scol ^ sxs), dst + j * 8192);
    }
  };

  short8 aF[4][2], bF0[2][2], bF1[2][2];
  auto LDA = [&](int mh, const char* bufA) {
#pragma unroll
    for (int j = 0; j < 4; j++) {
      int m = mh * 128 + wr * 64 + j * 16 + rl;
#pragma unroll
      for (int ks = 0; ks < 2; ks++)
        aF[j][ks] = *(const short8*)(bufA + m * 128 + ((ks * 64 + kg) ^ sx));
    }
  };
  auto LDB = [&](short8 (&bF)[2][2], int nh, const char* bufB) {
#pragma unroll
    for (int j2 = 0; j2 < 2; j2++) {
      int n = nh * 128 + wc * 32 + j2 * 16 + rl;
#pragma unroll
      for (int ks = 0; ks < 2; ks++)
        bF[j2][ks] = *(const short8*)(bufB + n * 128 + ((ks * 64 + kg) ^ sx));
    }
  };
  auto MM = [&](int mh, int nh, short8 (&bF)[2][2]) {
#pragma unroll
    for (int j = 0; j < 4; j++)
#pragma unroll
      for (int j2 = 0; j2 < 2; j2++)
#pragma unroll
        for (int ks = 0; ks < 2; ks++)
          acc[mh * 4 + j][nh * 2 + j2] = __builtin_amdgcn_mfma_f32_16x16x32_bf16(
              aF[j][ks], bF[j2][ks], acc[mh * 4 + j][nh * 2 + j2], 0, 0, 0);
  };

  const char* A0 = smem;
  const char* B0 = smem + 32768;
  const char* A1 = smem + 65536;
  const char* B1 = smem + 65536 + 32768;

  // Prologue: tile0 all 4 halves (oldest), tile1 {Ah0,Bh0,Bh1} = 14 loads.
  STG(0, 0, 0); STG(1, 0, 0); STG(1, 1, 0); STG(0, 1, 0);
  STG(0, 0, 1); STG(1, 0, 1); STG(1, 1, 1);
  VM6; SB;

#pragma unroll 1
  for (int t0 = 0; t0 < NKT; t0 += 2) {
    const bool more = (t0 + 2 < NKT);
    // P1: read A-mh0 + B-nh0 (buf0); stage Ah1(t0+1); mfma (0,0)
    LDA(0, A0); LDB(bF0, 0, B0); STG(0, 1, t0 + 1);
    SB; WLG; PRI1; MM(0, 0, bF0); PRI0; SB;
    // P2: read B-nh1 (buf0); stage Ah0(t0+2); mfma (0,1)
    LDB(bF1, 1, B0); STG(0, 0, t0 + 2);
    SB; WLG; PRI1; MM(0, 1, bF1); PRI0; SB;
    // P3: read A-mh1 (buf0); stage Bh0(t0+2); mfma (1,1)
    LDA(1, A0); STG(1, 0, t0 + 2);
    SB; WLG; PRI1; MM(1, 1, bF1); PRI0; SB;
    // P4: stage Bh1(t0+2); vmcnt -> tile t0+1 fully landed; mfma (1,0)
    STG(1, 1, t0 + 2);
    if (more) { VM6; } else { VM0; }
    SB; WLG; PRI1; MM(1, 0, bF0); PRI0; SB;
    // P5: tile t0+1 (buf1): read A-mh0 + B-nh0; stage Ah1(t0+2); mfma (0,0)
    LDA(0, A1); LDB(bF0, 0, B1); STG(0, 1, t0 + 2);
    SB; WLG; PRI1; MM(0, 0, bF0); PRI0; SB;
    // P6: read B-nh1 (buf1); stage Ah0(t0+3); mfma (0,1)
    LDB(bF1, 1, B1); STG(0, 0, t0 + 3);
    SB; WLG; PRI1; MM(0, 1, bF1); PRI0; SB;
    // P7: read A-mh1 (buf1); stage Bh0(t0+3); mfma (1,1)
    LDA(1, A1); STG(1, 0, t0 + 3);
    SB; WLG; PRI1; MM(1, 1, bF1); PRI0; SB;
    // P8: stage Bh1(t0+3); vmcnt -> tile t0+2 fully landed; mfma (1,0)
    STG(1, 1, t0 + 3);
    if (t0 + 3 < NKT) { VM6; } else { VM0; }
    SB; WLG; PRI1; MM(1, 0, bF0); PRI0; SB;
  }
}

// 8-phase epilogue coords: C/D frag: col = lane&15, row = (lane>>4)*4 + reg.
#define EPI8_COORDS                                       \
  const int lane = threadIdx.x & 63;                      \
  const int wid = threadIdx.x >> 6;                       \
  const int wr = wid >> 2, wc = wid & 3;                  \
  const int cl = lane & 15;                               \
  const int rg = (lane >> 4) * 4;

// Qc/Kc/Vc[8192][CW] = (xb @ W[:, h0*512 : +CW] + b) * scale   grid(32,CW/256,3)
template <int CHH>
__global__ __launch_bounds__(512, 2) void gemm_proj8_t(
    const bf16_t* __restrict__ xb, const bf16_t* __restrict__ Wt,
    bf16_t* __restrict__ Qc, bf16_t* __restrict__ Kc, bf16_t* __restrict__ Vc,
    const float* __restrict__ bq, const float* __restrict__ bk,
    const float* __restrict__ bv, int h0) {
  constexpr int CW = CHH * 512;
  extern __shared__ __align__(16) char dsm[];
  int z = blockIdx.z;
  const char* Ab = (const char*)xb;
  const char* Bb = (const char*)(Wt + ((size_t)z * F_N + h0 * 512) * K_N);
  int mbase = blockIdx.x * 256, nbase = blockIdx.y * 256;
  f32x4 acc[8][4];
  gemm_bt_8ph<8>(Ab, 1024, Bb, 1024, mbase, nbase, dsm, acc);

  bf16_t* C = z == 0 ? Qc : (z == 1 ? Kc : Vc);
  const float* bias = z == 0 ? bq : (z == 1 ? bk : bv);
  float scale = z < 2 ? SCALE_QK : 1.0f;
  EPI8_COORDS
#pragma unroll
  for (int nh = 0; nh < 2; nh++)
#pragma unroll
    for (int j2 = 0; j2 < 2; j2++) {
      int col = nbase + nh * 128 + wc * 32 + j2 * 16 + cl;
      float bvv = bias[h0 * 512 + col];
#pragma unroll
      for (int mh = 0; mh < 2; mh++)
#pragma unroll
        for (int j = 0; j < 4; j++)
#pragma unroll
          for (int ri = 0; ri < 4; ri++) {
            int row = mbase + mh * 128 + wr * 64 + j * 16 + rg + ri;
            C[(size_t)row * CW + col] =
                (bf16_t)((acc[mh * 4 + j][nh * 2 + j2][ri] + bvv) * scale);
          }
    }
}

// E[ze] = exp(Q_n K_n^T); L[n] += rowsums.   grid(8,8,NZ)
template <int CHH>
__global__ __launch_bounds__(512, 2) void gemm_s8_t(
    const bf16_t* __restrict__ Qc, const bf16_t* __restrict__ Kc,
    bf16_t* __restrict__ E, float* __restrict__ L, int h0, int zb) {
  constexpr int CW = CHH * 512;
  extern __shared__ __align__(16) char dsm[];
  int ze = blockIdx.z;
  int zc = zb + ze, b = zc & 3, hh = zc >> 2;
  const char* Ab = (const char*)(Qc + (size_t)(b * CHH + hh) * 512);
  const char* Bb = (const char*)(Kc + (size_t)(b * CHH + hh) * 512);
  int mbase = blockIdx.x * 256, nbase = blockIdx.y * 256;
  f32x4 acc[8][4];
  gemm_bt_8ph<8>(Ab, 8 * CW, Bb, 8 * CW, mbase, nbase, dsm, acc);

  bf16_t* C = E + (size_t)ze * T_N * T_N;
  float* Ln = L + ((h0 + hh) * 4 + b) * T_N;
  EPI8_COORDS
#pragma unroll
  for (int mh = 0; mh < 2; mh++)
#pragma unroll
    for (int j = 0; j < 4; j++)
#pragma unroll
      for (int ri = 0; ri < 4; ri++) {
        int row = mbase + mh * 128 + wr * 64 + j * 16 + rg + ri;
        float rs = 0.0f;
#pragma unroll
        for (int nh = 0; nh < 2; nh++)
#pragma unroll
          for (int j2 = 0; j2 < 2; j2++) {
            int col = nbase + nh * 128 + wc * 32 + j2 * 16 + cl;
            float e = __expf(acc[mh * 4 + j][nh * 2 + j2][ri]);  // |S| <~ 2.5
            rs += e;
            C[(size_t)row * T_N + col] = (bf16_t)e;
          }
#pragma unroll
        for (int off = 1; off < 16; off <<= 1) rs += __shfl_xor(rs, off, 16);
        if ((lane & 15) == 0) atomicAdd(Ln + row, rs);
      }
}

// ---------------------------------------------------------------------------
// 128^2 2-phase core (proven r3) — kept for gemm_pv (its grid at 256^2 would
// be only 128 blocks = half-GPU idle).
// ---------------------------------------------------------------------------
struct GemmAcc { f32x4 a[4][4]; };

__device__ __forceinline__ void gemm_bt_core(
    const char* __restrict__ Ab, size_t sA, const char* __restrict__ Bb, size_t sB,
    int mbase, int nbase, int NK, char* smem, GemmAcc& G) {
  const int tid = threadIdx.x;
  const int lane = tid & 63;
  const int wid = tid >> 6;
#pragma unroll
  for (int i = 0; i < 4; i++)
#pragma unroll
    for (int j = 0; j < 4; j++) G.a[i][j] = f32x4{0.f, 0.f, 0.f, 0.f};

  const int rsub = lane >> 3;
  const int qb = (lane & 7) * 16;

  auto stage = [&](int buf, int kt) {
    char* base = smem + buf * 32768;
#pragma unroll
    for (int it = 0; it < 4; it++) {
      int r = wid * 32 + it * 8 + rsub;
      const char* src = Ab + (size_t)(mbase + r) * sA + kt * 128 + (qb ^ ((r & 7) << 4));
      gll16(src, base + wid * 4096 + it * 1024);
    }
#pragma unroll
    for (int it = 0; it < 4; it++) {
      int r = wid * 32 + it * 8 + rsub;
      const char* src = Bb + (size_t)(nbase + r) * sB + kt * 128 + (qb ^ ((r & 7) << 4));
      gll16(src, base + 16384 + wid * 4096 + it * 1024);
    }
  };

  const int wm = wid >> 1, wn = wid & 1;
  const int rl = lane & 15;
  const int kg = (lane >> 4) * 16;

  auto compute = [&](int buf) {
    const char* base = smem + buf * 32768;
#pragma unroll
    for (int kf = 0; kf < 2; kf++) {
      int kb = kf * 64 + kg;
      short8 af[4], bfv[4];
#pragma unroll
      for (int mf = 0; mf < 4; mf++) {
        int m = wm * 64 + mf * 16 + rl;
        af[mf] = *(const short8*)(base + m * 128 + (kb ^ ((m & 7) << 4)));
      }
#pragma unroll
      for (int nf = 0; nf < 4; nf++) {
        int n = wn * 64 + nf * 16 + rl;
        bfv[nf] = *(const short8*)(base + 16384 + n * 128 + (kb ^ ((n & 7) << 4)));
      }
#pragma unroll
      for (int mf = 0; mf < 4; mf++)
#pragma unroll
        for (int nf = 0; nf < 4; nf++)
          G.a[mf][nf] = __builtin_amdgcn_mfma_f32_16x16x32_bf16(af[mf], bfv[nf],
                                                                G.a[mf][nf], 0, 0, 0);
    }
  };

  stage(0, 0);
  for (int kt = 0; kt < NK; kt++) {
    __syncthreads();
    if (kt + 1 < NK) stage((kt + 1) & 1, kt + 1);
    compute(kt & 1);
  }
}

#define EPILOGUE_COORDS                                   \
  const int lane = threadIdx.x & 63;                      \
  const int wid = threadIdx.x >> 6;                       \
  const int wm = wid >> 1, wn = wid & 1;                  \
  const int cl = lane & 15;                               \
  const int rg = (lane >> 4) * 4;

// ctxc cols of head (b,hh) = (E[ze] @ Vtc[zc]^T) / L    grid(16,4,NZ)
template <int CHH>
__global__ __launch_bounds__(256, 2) void gemm_pv_t(
    const bf16_t* __restrict__ E, const bf16_t* __restrict__ Vtc,
    const float* __restrict__ L, bf16_t* __restrict__ ctxc, int h0, int zb) {
  constexpr int CW = CHH * 512;
  __shared__ alignas(16) char smem[65536];
  int ze = blockIdx.z;
  int zc = zb + ze, b = zc & 3, hh = zc >> 2;
  const char* Ab = (const char*)(E + (size_t)ze * T_N * T_N);
  const char* Bb = (const char*)(Vtc + (size_t)zc * K_N * T_N);
  int mbase = blockIdx.x * 128, nbase = blockIdx.y * 128;
  GemmAcc G;
  gemm_bt_core(Ab, 4096, Bb, 4096, mbase, nbase, 32, smem, G);

  const float* Ln = L + ((h0 + hh) * 4 + b) * T_N;
  bf16_t* C = ctxc + (size_t)(b * CHH + hh) * 512;
  EPILOGUE_COORDS
#pragma unroll
  for (int mf = 0; mf < 4; mf++)
#pragma unroll
    for (int ri = 0; ri < 4; ri++) {
      int row = mbase + wm * 64 + mf * 16 + rg + ri;
      float inv = 1.0f / Ln[row];
#pragma unroll
      for (int nf = 0; nf < 4; nf++) {
        int col = nbase + wn * 64 + nf * 16 + cl;
        C[(size_t)row * 4 * CW + col] = (bf16_t)(G.a[mf][nf][ri] * inv);
      }
    }
}

// out[r][o] (+)= sum ctxc[r][.] * Wo[h0*512+.][o] (+bo first)
template <int CHH>
__global__ __launch_bounds__(256) void out_gemm_t(
    const bf16_t* __restrict__ ctxc, const float* __restrict__ Wo,
    const float* __restrict__ bo, float* __restrict__ out, int h0, int first) {
  constexpr int CW = CHH * 512;
  int tid = threadIdx.x, lane = tid & 63, wid = tid >> 6;
  int r = blockIdx.x * 4 + wid;
  const bf16_t* crow = ctxc + (size_t)r * CW + lane * (8 * CHH);
  const float* wbase = Wo + ((size_t)h0 * 512 + lane * (8 * CHH)) * 8;
  float p[8];
#pragma unroll
  for (int o = 0; o < 8; o++) p[o] = 0.0f;
#pragma unroll
  for (int j = 0; j < 8 * CHH; j += 8) {
    bf16x8 cv = *(const bf16x8*)(crow + j);
#pragma unroll
    for (int u = 0; u < 8; u++) {
      float c = (float)cv[u];
      const float* wrow = wbase + (j + u) * 8;
      f32x4 w0 = *(const f32x4*)wrow;
      f32x4 w1 = *(const f32x4*)(wrow + 4);
      p[0] += c * w0[0]; p[1] += c * w0[1]; p[2] += c * w0[2]; p[3] += c * w0[3];
      p[4] += c * w1[0]; p[5] += c * w1[1]; p[6] += c * w1[2]; p[7] += c * w1[3];
    }
  }
#pragma unroll
  for (int off = 1; off < 64; off <<= 1)
#pragma unroll
    for (int o = 0; o < 8; o++) p[o] += __shfl_xor(p[o], off, 64);
  if (lane == 0) {
#pragma unroll
    for (int o = 0; o < 8; o++) {
      float base = first ? bo[o] : out[r * 8 + o];
      out[r * 8 + o] = base + p[o];
    }
  }
}

// ---------------------------------------------------------------------------
template <int CHH>
static void run_chunks(const bf16_t* xb, const bf16_t* Wt, bf16_t* Qc, bf16_t* Kc,
                       bf16_t* Vc, bf16_t* Vtc, bf16_t* ctxc, bf16_t* E, float* L,
                       const float* bq, const float* bk, const float* bv,
                       const float* Wo, const float* bo, float* out, int NZ,
                       hipStream_t stream) {
  constexpr int CW = CHH * 512;
  hipFuncSetAttribute(reinterpret_cast<const void*>(gemm_proj8_t<CHH>),
                      hipFuncAttributeMaxDynamicSharedMemorySize, 131072);
  hipFuncSetAttribute(reinterpret_cast<const void*>(gemm_s8_t<CHH>),
                      hipFuncAttributeMaxDynamicSharedMemorySize, 131072);
  for (int c = 0; c < 8 / CHH; c++) {
    int h0 = c * CHH;
    gemm_proj8_t<CHH><<<dim3(32, CW / 256, 3), 512, 131072, stream>>>(
        xb, Wt, Qc, Kc, Vc, bq, bk, bv, h0);
    transpose_v_t<CHH><<<dim3(32, 8, 4 * CHH), 256, 0, stream>>>(Vc, Vtc);
    for (int zb = 0; zb < 4 * CHH; zb += NZ) {
      gemm_s8_t<CHH><<<dim3(8, 8, NZ), 512, 131072, stream>>>(Qc, Kc, E, L, h0, zb);
      gemm_pv_t<CHH><<<dim3(16, 4, NZ), 256, 0, stream>>>(E, Vtc, L, ctxc, h0, zb);
    }
    out_gemm_t<CHH><<<2048, 256, 0, stream>>>(ctxc, Wo, bo, out, h0, c == 0);
  }
}

extern "C" void kernel_launch(void* const* d_in, const int* in_sizes, int n_in,
                              void* d_out, int out_size, void* d_ws, size_t ws_size,
                              hipStream_t stream) {
  const float* x  = (const float*)d_in[0];
  const float* Wq = (const float*)d_in[1];
  const float* bq = (const float*)d_in[2];
  const float* Wk = (const float*)d_in[3];
  const float* bk = (const float*)d_in[4];
  const float* Wv = (const float*)d_in[5];
  const float* bv = (const float*)d_in[6];
  const float* Wo = (const float*)d_in[7];
  const float* bo = (const float*)d_in[8];
  float* out = (float*)d_out;
  char* ws = (char*)d_ws;

  const size_t MiB = 1ull << 20;
  int CHH, NZ;
  if      (ws_size >= 309 * MiB) { CHH = 4; NZ = 16; }
  else if (ws_size >= 165 * MiB) { CHH = 2; NZ = 8;  }
  else if (ws_size >= 93  * MiB) { CHH = 1; NZ = 4;  }
  else                           { CHH = 1; NZ = 1;  }

  size_t SZ = (size_t)CHH * 8 * MiB;
  bf16_t* xb   = (bf16_t*)(ws);
  bf16_t* Wt   = (bf16_t*)(ws + 8 * MiB);
  bf16_t* Qc   = (bf16_t*)(ws + 20 * MiB);
  bf16_t* Kc   = (bf16_t*)(ws + 20 * MiB + SZ);
  bf16_t* Vc   = (bf16_t*)(ws + 20 * MiB + 2 * SZ);
  bf16_t* Vtc  = (bf16_t*)(ws + 20 * MiB + 3 * SZ);
  bf16_t* ctxc = (bf16_t*)(ws + 20 * MiB + 4 * SZ);
  bf16_t* E    = (bf16_t*)(ws + 20 * MiB + 5 * SZ);
  float*  L    = (float*) (ws + 20 * MiB + 5 * SZ + (size_t)NZ * 8 * MiB);

  prep_x<<<2048, 256, 0, stream>>>(x, xb);
  prep_w<<<dim3(8, 64, 3), 256, 0, stream>>>(Wq, Wk, Wv, Wt);
  zero_l<<<256, 256, 0, stream>>>(L);

  if (CHH == 4)
    run_chunks<4>(xb, Wt, Qc, Kc, Vc, Vtc, ctxc, E, L, bq, bk, bv, Wo, bo, out, NZ, stream);
  else if (CHH == 2)
    run_chunks<2>(xb, Wt, Qc, Kc, Vc, Vtc, ctxc, E, L, bq, bk, bv, Wo, bo, out, NZ, stream);
  else
    run_chunks<1>(xb, Wt, Qc, Kc, Vc, Vtc, ctxc, E, L, bq, bk, bv, Wo, bo, out, NZ, stream);
}